// Round 6
// baseline (405.189 us; speedup 1.0000x reference)
//
#include <hip/hip_runtime.h>
#include <hip/hip_bf16.h>
#include <hip/hip_cooperative_groups.h>

namespace cg = cooperative_groups;

// Problem constants
constexpr int Bb = 4, Nn = 1024, Kk = 32;
constexpr int CS = 384, CZ = 128, CH = 16, Hh = 12, PQn = 4, PVn = 8;
constexpr int NCOLS = 1152;            // q(192)|k(192)|v(192)|qp(144)|kvp(432)
constexpr int FEAT = 960;              // o(192)|o_pt(288)|dists(96)|o_pair(384)
constexpr int NNODE = Bb * Nn;         // 4096
constexpr int NEDGE = NNODE * Kk;      // 131072
constexpr int ZOC = 44;                // zout cols: bbuf(12) | zd(32)
constexpr int NPREP = 1728 + 1440 + 1024 + 1;   // 4193 virtual prep blocks

// Workspace float offsets (flag occupies wsf[0..3]).  All offsets divisible by 4 (16B align).
constexpr int O_WZP   = 4;                            // [128][48] LN-scale-folded [wb|wdz]
constexpr int O_BVEC  = O_WZP + 6144;                 // [48]
constexpr int O_CSUM  = O_BVEC + 48;                  // [48]
constexpr int O_P     = O_CSUM + 48;                  // [4096][1152] f32
constexpr int O_ZOUT  = O_P + NNODE * NCOLS;          // [131072][44] f32
constexpr int O_SLNH  = O_ZOUT + NEDGE * ZOC;         // [4096][384] ushort (bf16 hi)
constexpr int O_SLNL  = O_SLNH + NNODE * CS / 2;      // [4096][384] ushort (bf16 lo)
constexpr int O_WNTH  = O_SLNL + NNODE * CS / 2;      // [1152][384] ushort (W_node^T hi)
constexpr int O_WNTL  = O_WNTH + NCOLS * CS / 2;      // [1152][384] ushort
constexpr int O_WOTH  = O_WNTL + NCOLS * CS / 2;      // [384][960] ushort (w_out^T hi)
constexpr int O_WOTL  = O_WOTH + CS * FEAT / 2;       // [384][960] ushort
// feat hi aliases sln/wnodeT (dead after P-GEMM): 1.97M < 2.01M floats available
constexpr int O_FEATH = O_SLNH;                       // [4096][960] ushort
constexpr int O_FEATL = O_WOTL + CS * FEAT / 2;       // [4096][960] ushort
constexpr int TOTAL_F = O_FEATL + NNODE * FEAT / 2;   // ~14.84M floats = 59.4 MB

typedef __attribute__((ext_vector_type(8)))  short short8x;
typedef __attribute__((ext_vector_type(16))) float f32x16;

__device__ __forceinline__ float ldf(const float* p, int i) { return p[i]; }
__device__ __forceinline__ float ldf(const __hip_bfloat16* p, int i) { return __bfloat162float(p[i]); }
__device__ __forceinline__ void stf(float* p, size_t i, float v) { p[i] = v; }
__device__ __forceinline__ void stf(__hip_bfloat16* p, size_t i, float v) { p[i] = __float2bfloat16(v); }
__device__ __forceinline__ float4 ld4(const float* p, size_t i) { return *(const float4*)(p + i); }
__device__ __forceinline__ float4 ld4(const __hip_bfloat16* p, size_t i) {
    ushort4 u = *(const ushort4*)(p + i);
    return make_float4(__uint_as_float((unsigned)u.x << 16),
                       __uint_as_float((unsigned)u.y << 16),
                       __uint_as_float((unsigned)u.z << 16),
                       __uint_as_float((unsigned)u.w << 16));
}
// Split f32 -> bf16 hi (truncate) + bf16 lo (residual, truncate).
__device__ __forceinline__ void split_bf(float v, unsigned short& h, unsigned short& l) {
    h = (unsigned short)(__float_as_uint(v) >> 16);
    float r = v - __uint_as_float((unsigned)h << 16);
    l = (unsigned short)(__float_as_uint(r) >> 16);
}

// Fallback dtype detect from s_mask (all ones): f32 -> 0x3F800000, bf16x2 -> 0x3F803F80
__global__ void k_detect(const unsigned* smask_raw, int* flag) {
    if (threadIdx.x == 0) *flag = (smask_raw[0] == 0x3F803F80u) ? 1 : 0;
}

// ---------------- Phase A: prep (virtual blocks, 256 threads) ----------------
// vb [0,1728):      wnodeT hi/lo elementwise (442368 elems)
// vb [1728,3168):   woutT hi/lo elementwise (368640 elems)
// vb [3168,4192):   s LayerNorm, 4 rows/block, wave-per-row (no LDS)
// vb 4192:          z-weight prep (W' = diag(zsc)@[wb|wdz], bvec, csum)
template <typename T>
__device__ __forceinline__ void dev_prep(int vb, int t,
    const T* s, const T* lns_sc, const T* lns_bi,
    const T* wq, const T* wk, const T* wv, const T* wqp, const T* wkvp, const T* wout,
    const T* wb, const T* wdz, const T* zsc, const T* zbi, float* wsf)
{
    unsigned short* wntH = (unsigned short*)(wsf + O_WNTH);
    unsigned short* wntL = (unsigned short*)(wsf + O_WNTL);
    unsigned short* wotH = (unsigned short*)(wsf + O_WOTH);
    unsigned short* wotL = (unsigned short*)(wsf + O_WOTL);
    unsigned short* slnH = (unsigned short*)(wsf + O_SLNH);
    unsigned short* slnL = (unsigned short*)(wsf + O_SLNL);
    if (vb < 1728) {
        int idx = vb * 256 + t;                     // exactly 1152*384
        int n = idx / 384, k = idx - n * 384;
        float v;
        if      (n < 192) v = ldf(wq,  k * 192 + n);
        else if (n < 384) v = ldf(wk,  k * 192 + n - 192);
        else if (n < 576) v = ldf(wv,  k * 192 + n - 384);
        else if (n < 720) v = ldf(wqp, k * 144 + n - 576);
        else              v = ldf(wkvp, k * 432 + n - 720);
        unsigned short h, l; split_bf(v, h, l);
        wntH[n * 384 + k] = h; wntL[n * 384 + k] = l;
    } else if (vb < 3168) {
        int idx = (vb - 1728) * 256 + t;            // exactly 384*960
        int n = idx / 960, k = idx - n * 960;
        float v = ldf(wout, k * 384 + n);
        unsigned short h, l; split_bf(v, h, l);
        wotH[n * 960 + k] = h; wotL[n * 960 + k] = l;
    } else if (vb < 4192) {
        int row = (vb - 3168) * 4 + (t >> 6), lane = t & 63;
        float x[6]; float sum = 0, sq = 0;
        #pragma unroll
        for (int j = 0; j < 6; j++) {
            float v = ldf(s, row * CS + lane + 64 * j);
            x[j] = v; sum += v; sq += v * v;
        }
        #pragma unroll
        for (int m = 32; m; m >>= 1) { sum += __shfl_xor(sum, m, 64); sq += __shfl_xor(sq, m, 64); }
        float mean = sum * (1.f / CS);
        float var  = sq * (1.f / CS) - mean * mean;
        float r = rsqrtf(var + 1e-5f);
        #pragma unroll
        for (int j = 0; j < 6; j++) {
            int c = lane + 64 * j;
            float y = (x[j] - mean) * r * ldf(lns_sc, c) + ldf(lns_bi, c);
            unsigned short h, l; split_bf(y, h, l);
            slnH[(size_t)row * CS + c] = h; slnL[(size_t)row * CS + c] = l;
        }
    } else {
        if (t < 128) {
            float sc = ldf(zsc, t);
            for (int o = 0; o < 48; o++) {
                float w = 0.f;
                if (o < 12)      w = ldf(wb, t * 12 + o);
                else if (o < 44) w = ldf(wdz, t * 32 + o - 12);
                wsf[O_WZP + t * 48 + o] = sc * w;
            }
        } else if (t < 176) {
            int o = t - 128;
            float acc = 0.f;
            if (o < 44)
                for (int c = 0; c < 128; c++)
                    acc += ldf(zbi, c) * (o < 12 ? ldf(wb, c * 12 + o) : ldf(wdz, c * 32 + o - 12));
            wsf[O_BVEC + o] = acc;
        } else if (t < 224) {
            int o = t - 176;
            float acc = 0.f;
            if (o < 44)
                for (int c = 0; c < 128; c++)
                    acc += ldf(zsc, c) * (o < 12 ? ldf(wb, c * 12 + o) : ldf(wdz, c * 32 + o - 12));
            wsf[O_CSUM + o] = acc;
        }
    }
}

// ---------------- Phase B: z-GEMM + fused LN, 128 edges / 256-thread block --------------
// Needs sm[8512] f32: Ws[6144] | As[16][132] | mus[128] | rss[128]
template <typename T>
__device__ void dev_zg(int vb, int t, const T* z, const float* wzp, const float* bvec,
                       const float* csum, float* zout, float* sm)
{
    float* Ws  = sm;
    float* Asf = sm + 6144;
    float* mus = sm + 6144 + 2112;
    float* rss = mus + 128;
    int edge0 = vb * 128;
    for (int i = t; i < 6144; i += 256) Ws[i] = wzp[i];
    int sr = t >> 1, q = t & 1;
    int r0 = (t >> 2) * 2, col = (t & 3) * 12;
    float psum = 0, psq = 0;
    float acc[2][12] = {};
    for (int kt = 0; kt < CZ; kt += 16) {
        float4 z0 = ld4(z, (size_t)(edge0 + sr) * CZ + kt + q * 8);
        float4 z1 = ld4(z, (size_t)(edge0 + sr) * CZ + kt + q * 8 + 4);
        psum += z0.x + z0.y + z0.z + z0.w + z1.x + z1.y + z1.z + z1.w;
        psq  += z0.x*z0.x + z0.y*z0.y + z0.z*z0.z + z0.w*z0.w
              + z1.x*z1.x + z1.y*z1.y + z1.z*z1.z + z1.w*z1.w;
        __syncthreads();
        Asf[(q * 8 + 0) * 132 + sr] = z0.x;
        Asf[(q * 8 + 1) * 132 + sr] = z0.y;
        Asf[(q * 8 + 2) * 132 + sr] = z0.z;
        Asf[(q * 8 + 3) * 132 + sr] = z0.w;
        Asf[(q * 8 + 4) * 132 + sr] = z1.x;
        Asf[(q * 8 + 5) * 132 + sr] = z1.y;
        Asf[(q * 8 + 6) * 132 + sr] = z1.z;
        Asf[(q * 8 + 7) * 132 + sr] = z1.w;
        __syncthreads();
        #pragma unroll
        for (int kk = 0; kk < 16; kk++) {
            float a0 = Asf[kk * 132 + r0], a1 = Asf[kk * 132 + r0 + 1];
            const float* wr = &Ws[(kt + kk) * 48 + col];
            float4 b0 = *(const float4*)(wr);
            float4 b1 = *(const float4*)(wr + 4);
            float4 b2 = *(const float4*)(wr + 8);
            float bv[12] = {b0.x,b0.y,b0.z,b0.w,b1.x,b1.y,b1.z,b1.w,b2.x,b2.y,b2.z,b2.w};
            #pragma unroll
            for (int j = 0; j < 12; j++) { acc[0][j] += a0 * bv[j]; acc[1][j] += a1 * bv[j]; }
        }
    }
    psum += __shfl_xor(psum, 1, 64);
    psq  += __shfl_xor(psq, 1, 64);
    if (q == 0) {
        float mu = psum * (1.f / CZ);
        mus[sr] = mu;
        rss[sr] = rsqrtf(psq * (1.f / CZ) - mu * mu + 1e-5f);
    }
    __syncthreads();
    #pragma unroll
    for (int i = 0; i < 2; i++) {
        int r = r0 + i;
        float mu = mus[r], rs = rss[r];
        size_t e = edge0 + r;
        #pragma unroll
        for (int j = 0; j < 12; j++) {
            int c = col + j;
            if (c < ZOC) zout[e * ZOC + c] = rs * acc[i][j] - rs * mu * csum[c] + bvec[c];
        }
    }
    __syncthreads();
}

// ---------------- MFMA split-bf16 64x64 tile (one wave, no LDS, no prefetch regs) -------
#define MFMA3(C, AH, AL, BH, BL)                                              \
    C = __builtin_amdgcn_mfma_f32_32x32x16_bf16(AH, BH, C, 0, 0, 0);          \
    C = __builtin_amdgcn_mfma_f32_32x32x16_bf16(AH, BL, C, 0, 0, 0);          \
    C = __builtin_amdgcn_mfma_f32_32x32x16_bf16(AL, BH, C, 0, 0, 0);

template <typename TO>
__device__ void dev_mgemm_tile(int bx, int by, int l,
                               const unsigned short* AH, const unsigned short* AL, int lda,
                               const unsigned short* BH, const unsigned short* BL, int ldb,
                               TO* C, int ldc, int Kdim)
{
    int r = l & 31, g = l >> 5;
    size_t a0 = (size_t)(bx * 64 + r) * lda + 8 * g;
    size_t a1 = a0 + (size_t)32 * lda;
    size_t b0 = (size_t)(by * 64 + r) * ldb + 8 * g;
    size_t b1 = b0 + (size_t)32 * ldb;
    f32x16 c00 = {}, c01 = {}, c10 = {}, c11 = {};
    for (int kt = 0; kt < Kdim; kt += 16) {
        short8x aH0 = *(const short8x*)(AH + a0 + kt), aH1 = *(const short8x*)(AH + a1 + kt);
        short8x aL0 = *(const short8x*)(AL + a0 + kt), aL1 = *(const short8x*)(AL + a1 + kt);
        short8x bH0 = *(const short8x*)(BH + b0 + kt), bH1 = *(const short8x*)(BH + b1 + kt);
        short8x bL0 = *(const short8x*)(BL + b0 + kt), bL1 = *(const short8x*)(BL + b1 + kt);
        MFMA3(c00, aH0, aL0, bH0, bL0)
        MFMA3(c01, aH0, aL0, bH1, bL1)
        MFMA3(c10, aH1, aL1, bH0, bL0)
        MFMA3(c11, aH1, aL1, bH1, bL1)
    }
    // D layout: col = lane&31, row = (reg&3) + 8*(reg>>2) + 4*(lane>>5)
    #pragma unroll
    for (int reg = 0; reg < 16; reg++) {
        int row = (reg & 3) + 8 * (reg >> 2) + 4 * g;
        size_t rm = (size_t)(bx * 64 + row);
        int cn = by * 64 + r;
        stf(C, rm * ldc + cn,             c00[reg]);
        stf(C, rm * ldc + cn + 32,        c01[reg]);
        stf(C, (rm + 32) * ldc + cn,      c10[reg]);
        stf(C, (rm + 32) * ldc + cn + 32, c11[reg]);
    }
}

// ---------------- Phase D: attention, one wave per node ---------------------------------
// smAll: >= 4*1760 f32; jsAll: >= 4*32 int
template <typename T>
__device__ void dev_attn(int bid, int t, float* smAll, int* jsAll,
                         const float* P, const float* zout, const int* eidx,
                         const T* smask, const T* rot, const T* hwq,
                         unsigned short* featH, unsigned short* featL)
{
    int nb = ((bid & 7) << 7) + (bid >> 3);   // XCD-chunked swizzle (1024 = 8*128, bijective)
    int w = t >> 6, lane = t & 63;
    int node = nb * 4 + w;
    int b = node >> 10;
    float* S = smAll + w * 1760;
    int* J = jsAll + w * 32;
    const float* Pn = P + (size_t)node * NCOLS;
    for (int u = lane; u < 336; u += 64)
        S[u] = (u < 192) ? Pn[u] : Pn[384 + u];           // q | q_pts (cols 576..719)
    if (lane < 32) {
        int j = eidx[node * Kk + lane];
        J[lane] = b * Nn + j;
        S[360 + lane] = ldf(smask, node) * ldf(smask, b * Nn + j);
    } else if (lane < 44) {
        int h = lane - 32;
        float x = ldf(hwq, h);
        S[336 + h] = logf(1.f + expf(x)) * 0.13608276348795434f;   // softplus * sqrt(1/54)
    } else if (lane < 53) {
        int u = lane - 44;
        int i = u / 3, jj = u - i * 3;
        float m = 0;
        #pragma unroll
        for (int l2 = 0; l2 < 3; l2++)
            m += ldf(rot, node * 9 + l2 * 3 + i) * ldf(rot, node * 9 + l2 * 3 + jj);
        S[348 + u] = m;                                    // M = R^T R
    }
    __builtin_amdgcn_wave_barrier();
    #pragma unroll
    for (int it = 0; it < 6; it++) {
        int u = lane + 64 * it;
        int h = u >> 5, k = u & 31;
        const float* Pj = P + (size_t)J[k] * NCOLS;
        float qk = 0;
        const float4* pk4 = (const float4*)(Pj + 192 + h * 16);
        const float4* qs4 = (const float4*)(S + h * 16);
        #pragma unroll
        for (int c4 = 0; c4 < 4; c4++) {
            float4 pv = pk4[c4], qv = qs4[c4];
            qk += qv.x * pv.x + qv.y * pv.y + qv.z * pv.z + qv.w * pv.w;
        }
        float M00 = S[348], M01 = S[349], M02 = S[350],
              M11 = S[352], M12 = S[353], M22 = S[356];
        const float4* pp4 = (const float4*)(Pj + 720 + h * 36);
        const float4* qp4 = (const float4*)(S + 192 + h * 12);
        float4 A0 = pp4[0], A1 = pp4[1], A2 = pp4[2];
        float4 B0 = qp4[0], B1 = qp4[1], B2 = qp4[2];
        float d[12] = {B0.x - A0.x, B0.y - A0.y, B0.z - A0.z, B0.w - A0.w,
                       B1.x - A1.x, B1.y - A1.y, B1.z - A1.z, B1.w - A1.w,
                       B2.x - A2.x, B2.y - A2.y, B2.z - A2.z, B2.w - A2.w};
        float sq = 0;
        #pragma unroll
        for (int p = 0; p < 4; p++) {
            float d0 = d[p * 3], d1 = d[p * 3 + 1], d2 = d[p * 3 + 2];
            sq += M00 * d0 * d0 + M11 * d1 * d1 + M22 * d2 * d2
                + 2.f * (M01 * d0 * d1 + M02 * d0 * d2 + M12 * d1 * d2);
        }
        float logit = qk * 0.14433756729740643f
                    + 0.5773502691896258f * zout[((size_t)node * Kk + k) * ZOC + h]
                    - 0.5f * S[336 + h] * sq
                    + 1e5f * (S[360 + k] - 1.f);
        float mx = logit;
        #pragma unroll
        for (int m = 16; m; m >>= 1) mx = fmaxf(mx, __shfl_xor(mx, m, 64));
        float e = expf(logit - mx);
        float ssum = e;
        #pragma unroll
        for (int m = 16; m; m >>= 1) ssum += __shfl_xor(ssum, m, 64);
        S[392 + h * 33 + k] = e / ssum;                    // stride-33: conflict-free
    }
    __builtin_amdgcn_wave_barrier();
    for (int u = lane; u < 216; u += 64) {
        int h, off, fbase, pair = 0;
        if (u < 48)       { h = u >> 2; off = 384 + h * 16 + (u & 3) * 4; fbase = h * 16 + (u & 3) * 4; }
        else if (u < 120) { int v = u - 48;  h = v / 6; int q = v - h * 6;
                            off = 732 + h * 36 + q * 4; fbase = 192 + h * 24 + q * 4; }
        else              { int v = u - 120; h = v >> 3;
                            off = 12 + (v & 7) * 4; fbase = 576 + h * 32 + (v & 7) * 4; pair = 1; }
        float4 acc = {0.f, 0.f, 0.f, 0.f};
        const float* lrow = S + 392 + h * 33;
        if (!pair) {
            #pragma unroll 8
            for (int k = 0; k < 32; k++) {
                float lw = lrow[k];
                float4 pv = *(const float4*)(P + (size_t)J[k] * NCOLS + off);
                acc.x += lw * pv.x; acc.y += lw * pv.y; acc.z += lw * pv.z; acc.w += lw * pv.w;
            }
        } else {
            const float* zr = zout + (size_t)node * Kk * ZOC + off;
            #pragma unroll 8
            for (int k = 0; k < 32; k++) {
                float lw = lrow[k];
                float4 pv = *(const float4*)(zr + k * ZOC);
                acc.x += lw * pv.x; acc.y += lw * pv.y; acc.z += lw * pv.z; acc.w += lw * pv.w;
            }
        }
        *(float4*)&S[788 + fbase] = acc;
    }
    __builtin_amdgcn_wave_barrier();
    for (int u = lane; u < 96; u += 64) {
        float r0 = S[788 + 192 + u * 3 + 0];
        float r1 = S[788 + 192 + u * 3 + 1];
        float r2 = S[788 + 192 + u * 3 + 2];
        float o0 = S[348] * r0 + S[349] * r1 + S[350] * r2;
        float o1 = S[351] * r0 + S[352] * r1 + S[353] * r2;
        float o2 = S[354] * r0 + S[355] * r1 + S[356] * r2;
        S[788 + 192 + u * 3 + 0] = o0;
        S[788 + 192 + u * 3 + 1] = o1;
        S[788 + 192 + u * 3 + 2] = o2;
        S[788 + 480 + u] = sqrtf(o0 * o0 + o1 * o1 + o2 * o2 + 1e-8f);
    }
    __builtin_amdgcn_wave_barrier();
    for (int u = lane; u < FEAT; u += 64) {
        unsigned short h, l; split_bf(S[788 + u], h, l);
        featH[(size_t)node * FEAT + u] = h;
        featL[(size_t)node * FEAT + u] = l;
    }
}

// ---------------- Fused cooperative mega-kernel -----------------------------------------
template <typename T, typename TO>
__global__ __launch_bounds__(256, 4) void k_fused(const T* s, const T* z, const int* eidx,
    const T* rot, const T* smask, const T* lns_sc, const T* lns_bi,
    const T* wq, const T* wk, const T* wv, const T* wqp, const T* wkvp,
    const T* wb, const T* wdz, const T* zsc, const T* zbi, const T* hwq, const T* wout,
    float* wsf, TO* out)
{
    __shared__ float sm[8512];
    __shared__ int js[4][32];
    cg::grid_group gg = cg::this_grid();
    int bid = blockIdx.x, t = threadIdx.x;

    // Phase A: prep
    for (int vb = bid; vb < NPREP; vb += 1024)
        dev_prep<T>(vb, t, s, lns_sc, lns_bi, wq, wk, wv, wqp, wkvp, wout, wb, wdz, zsc, zbi, wsf);
    gg.sync();

    // Phase B: z-GEMM (+LN), 128 edges per block, all 1024 blocks
    dev_zg<T>(bid, t, z, wsf + O_WZP, wsf + O_BVEC, wsf + O_CSUM, wsf + O_ZOUT, sm);
    gg.sync();

    const unsigned short* slnH = (const unsigned short*)(wsf + O_SLNH);
    const unsigned short* slnL = (const unsigned short*)(wsf + O_SLNL);
    const unsigned short* wntH = (const unsigned short*)(wsf + O_WNTH);
    const unsigned short* wntL = (const unsigned short*)(wsf + O_WNTL);
    const unsigned short* wotH = (const unsigned short*)(wsf + O_WOTH);
    const unsigned short* wotL = (const unsigned short*)(wsf + O_WOTL);
    unsigned short* featH = (unsigned short*)(wsf + O_FEATH);
    unsigned short* featL = (unsigned short*)(wsf + O_FEATL);

    // Phase C: P = sln @ Wnode (wave-tiles, 64x18 = 1152 tiles)
    {
        int w = t >> 6, lane = t & 63;
        int wid = bid * 4 + w;
        for (int tile = wid; tile < 64 * 18; tile += 4096)
            dev_mgemm_tile<float>(tile & 63, tile >> 6, lane, slnH, slnL, CS, wntH, wntL, CS,
                                  wsf + O_P, NCOLS, CS);
    }
    gg.sync();

    // Phase D: attention (4 nodes per block)
    dev_attn<T>(bid, t, sm, &js[0][0], wsf + O_P, wsf + O_ZOUT, eidx, smask, rot, hwq, featH, featL);
    gg.sync();

    // Phase E: out = feat @ w_out (64x6 = 384 tiles)
    {
        int w = t >> 6, lane = t & 63;
        int wid = bid * 4 + w;
        for (int tile = wid; tile < 64 * 6; tile += 4096)
            dev_mgemm_tile<TO>(tile & 63, tile >> 6, lane, featH, featL, FEAT, wotH, wotL, FEAT,
                               out, CS, FEAT);
    }
}

// ---------------- Standalone fallback wrappers ------------------------------------------
template <typename T>
__global__ __launch_bounds__(256) void k_prep_s(const T* s, const T* lns_sc, const T* lns_bi,
    const T* wq, const T* wk, const T* wv, const T* wqp, const T* wkvp, const T* wout,
    const T* wb, const T* wdz, const T* zsc, const T* zbi, float* wsf, const int* flag, int want) {
    if (flag && *flag != want) return;
    dev_prep<T>(blockIdx.x, threadIdx.x, s, lns_sc, lns_bi, wq, wk, wv, wqp, wkvp, wout,
                wb, wdz, zsc, zbi, wsf);
}

template <typename T>
__global__ __launch_bounds__(256) void k_zg_s(const T* z, const float* wzp, const float* bvec,
    const float* csum, float* zout, const int* flag, int want) {
    if (flag && *flag != want) return;
    __shared__ float sm[8512];
    dev_zg<T>(blockIdx.x, threadIdx.x, z, wzp, bvec, csum, zout, sm);
}

template <typename TO>
__global__ __launch_bounds__(64) void k_mgemm_s(const unsigned short* AH, const unsigned short* AL,
    int lda, const unsigned short* BH, const unsigned short* BL, int ldb,
    TO* C, int ldc, int Kdim, const int* flag, int want) {
    if (flag && *flag != want) return;
    dev_mgemm_tile<TO>(blockIdx.x, blockIdx.y, threadIdx.x, AH, AL, lda, BH, BL, ldb, C, ldc, Kdim);
}

template <typename T>
__global__ __launch_bounds__(256) void k_attn_s(const float* P, const float* zout, const int* eidx,
    const T* smask, const T* rot, const T* hwq, unsigned short* featH, unsigned short* featL,
    const int* flag, int want) {
    if (flag && *flag != want) return;
    __shared__ float sm[7040];
    __shared__ int js[4][32];
    dev_attn<T>(blockIdx.x, threadIdx.x, sm, &js[0][0], P, zout, eidx, smask, rot, hwq, featH, featL);
}

// ---------------- Host side -------------------------------------------------------------
template <typename T, typename TO>
static void run_path(const void* s, const void* z, const int* eidx, const void* rot,
                     const void* smask, const void* lns_sc, const void* lns_bi,
                     const void* wq, const void* wk, const void* wv, const void* wqp,
                     const void* wkvp, const void* wb, const void* wdz, const void* zsc,
                     const void* zbi, const void* hwq, const void* wout,
                     float* wsf, void* dout, const int* fg, int want, bool try_coop,
                     hipStream_t stream)
{
    unsigned short* slnH = (unsigned short*)(wsf + O_SLNH);
    unsigned short* slnL = (unsigned short*)(wsf + O_SLNL);
    unsigned short* wntH = (unsigned short*)(wsf + O_WNTH);
    unsigned short* wntL = (unsigned short*)(wsf + O_WNTL);
    unsigned short* wotH = (unsigned short*)(wsf + O_WOTH);
    unsigned short* wotL = (unsigned short*)(wsf + O_WOTL);
    unsigned short* featH = (unsigned short*)(wsf + O_FEATH);
    unsigned short* featL = (unsigned short*)(wsf + O_FEATL);

    if (try_coop) {
        const T *sP = (const T*)s, *zP = (const T*)z, *rotP = (const T*)rot,
                *smP = (const T*)smask, *lsP = (const T*)lns_sc, *lbP = (const T*)lns_bi,
                *wqP = (const T*)wq, *wkP = (const T*)wk, *wvP = (const T*)wv,
                *wqpP = (const T*)wqp, *wkvpP = (const T*)wkvp, *wbP = (const T*)wb,
                *wdzP = (const T*)wdz, *zscP = (const T*)zsc, *zbiP = (const T*)zbi,
                *hwqP = (const T*)hwq, *woP = (const T*)wout;
        const int* eP = eidx;
        float* wsP = wsf;
        TO* oP = (TO*)dout;
        void* prm[20] = {&sP, &zP, &eP, &rotP, &smP, &lsP, &lbP, &wqP, &wkP, &wvP,
                         &wqpP, &wkvpP, &wbP, &wdzP, &zscP, &zbiP, &hwqP, &woP, &wsP, &oP};
        hipError_t err = hipLaunchCooperativeKernel(
            reinterpret_cast<void*>(&k_fused<T, TO>), dim3(1024), dim3(256), prm, 0, stream);
        if (err == hipSuccess) return;
        (void)hipGetLastError();   // clear sticky error, fall through to standalone
    }

    k_prep_s<T><<<NPREP, 256, 0, stream>>>((const T*)s, (const T*)lns_sc, (const T*)lns_bi,
        (const T*)wq, (const T*)wk, (const T*)wv, (const T*)wqp, (const T*)wkvp,
        (const T*)wout, (const T*)wb, (const T*)wdz, (const T*)zsc, (const T*)zbi, wsf, fg, want);
    k_zg_s<T><<<1024, 256, 0, stream>>>((const T*)z, wsf + O_WZP, wsf + O_BVEC, wsf + O_CSUM,
        wsf + O_ZOUT, fg, want);
    k_mgemm_s<float><<<dim3(64, 18), 64, 0, stream>>>(slnH, slnL, CS, wntH, wntL, CS,
        wsf + O_P, NCOLS, CS, (const int*)nullptr, 0);
    k_attn_s<T><<<1024, 256, 0, stream>>>(wsf + O_P, wsf + O_ZOUT, eidx, (const T*)smask,
        (const T*)rot, (const T*)hwq, featH, featL, fg, want);
    k_mgemm_s<TO><<<dim3(64, 6), 64, 0, stream>>>(featH, featL, FEAT, wotH, wotL, FEAT,
        (TO*)dout, CS, FEAT, fg, want);
}

extern "C" void kernel_launch(void* const* d_in, const int* in_sizes, int n_in,
                              void* d_out, int out_size, void* d_ws, size_t ws_size,
                              hipStream_t stream) {
    float* wsf = (float*)d_ws;
    int* flag = (int*)d_ws;
    const void* s = d_in[0];   const void* z = d_in[1];
    const int* eidx = (const int*)d_in[2];
    const void* rot = d_in[3];                         // d_in[4] trans: unused (cancels exactly)
    const void* smask = d_in[5];
    const void* lns_sc = d_in[6]; const void* lns_bi = d_in[7];
    const void* lnz_sc = d_in[8]; const void* lnz_bi = d_in[9];
    const void* wq = d_in[10]; const void* wk = d_in[11]; const void* wv = d_in[12];
    const void* wqp = d_in[13]; const void* wkvp = d_in[14];
    const void* wb = d_in[15]; const void* wdz = d_in[16];
    const void* hwq = d_in[17]; const void* wout = d_in[18];

    int mode = -1;  // 0 = f32, 1 = bf16, -1 = unknown -> guarded dual standalone
    if (in_sizes) {
        if (in_sizes[0] == NNODE * CS * 4) mode = 0;
        else if (in_sizes[0] == NNODE * CS * 2) mode = 1;
    }

    if (mode == 0) {
        run_path<float, float>(s, z, eidx, rot, smask, lns_sc, lns_bi, wq, wk, wv, wqp, wkvp,
                               wb, wdz, lnz_sc, lnz_bi, hwq, wout, wsf, d_out,
                               nullptr, 0, true, stream);
    } else if (mode == 1) {
        run_path<__hip_bfloat16, __hip_bfloat16>(s, z, eidx, rot, smask, lns_sc, lns_bi,
                               wq, wk, wv, wqp, wkvp, wb, wdz, lnz_sc, lnz_bi, hwq, wout,
                               wsf, d_out, nullptr, 0, true, stream);
    } else {
        k_detect<<<1, 64, 0, stream>>>((const unsigned*)smask, flag);
        run_path<float, float>(s, z, eidx, rot, smask, lns_sc, lns_bi, wq, wk, wv, wqp, wkvp,
                               wb, wdz, lnz_sc, lnz_bi, hwq, wout, wsf, d_out,
                               flag, 0, false, stream);
        run_path<__hip_bfloat16, __hip_bfloat16>(s, z, eidx, rot, smask, lns_sc, lns_bi,
                               wq, wk, wv, wqp, wkvp, wb, wdz, lnz_sc, lnz_bi, hwq, wout,
                               wsf, d_out, flag, 1, false, stream);
    }
}

// Round 7
// 336.962 us; speedup vs baseline: 1.2025x; 1.2025x over previous
//
#include <hip/hip_runtime.h>
#include <hip/hip_bf16.h>

// Problem constants
constexpr int Bb = 4, Nn = 1024, Kk = 32;
constexpr int CS = 384, CZ = 128, CH = 16, Hh = 12, PQn = 4, PVn = 8;
constexpr int NCOLS = 1152;            // q(192)|k(192)|v(192)|qp(144)|kvp(432)
constexpr int FEAT = 960;              // o(192)|o_pt(288)|dists(96)|o_pair(384)
constexpr int NNODE = Bb * Nn;         // 4096
constexpr int NEDGE = NNODE * Kk;      // 131072
constexpr int ZOC = 44;                // zout cols: bbuf(12) | zd(32)
constexpr int NPREP = 1728 + 1440 + 1024 + 1;   // 4193 prep blocks

// Workspace float offsets (flag occupies wsf[0..3]).  All offsets divisible by 4 (16B align).
constexpr int O_WZP   = 4;                            // [128][48] LN-scale-folded [wb|wdz]
constexpr int O_BVEC  = O_WZP + 6144;                 // [48]
constexpr int O_CSUM  = O_BVEC + 48;                  // [48]
constexpr int O_P     = O_CSUM + 48;                  // [4096][1152] f32
constexpr int O_ZOUT  = O_P + NNODE * NCOLS;          // [131072][44] f32
constexpr int O_SLNH  = O_ZOUT + NEDGE * ZOC;         // [4096][384] ushort (bf16 hi)
constexpr int O_SLNL  = O_SLNH + NNODE * CS / 2;      // [4096][384] ushort (bf16 lo)
constexpr int O_WNTH  = O_SLNL + NNODE * CS / 2;      // [1152][384] ushort (W_node^T hi)
constexpr int O_WNTL  = O_WNTH + NCOLS * CS / 2;      // [1152][384] ushort
constexpr int O_WOTH  = O_WNTL + NCOLS * CS / 2;      // [384][960] ushort (w_out^T hi)
constexpr int O_WOTL  = O_WOTH + CS * FEAT / 2;       // [384][960] ushort
// feat hi aliases sln/wnodeT (dead after P-GEMM): 1.97M < 2.01M floats available
constexpr int O_FEATH = O_SLNH;                       // [4096][960] ushort
constexpr int O_FEATL = O_WOTL + CS * FEAT / 2;       // [4096][960] ushort
constexpr int TOTAL_F = O_FEATL + NNODE * FEAT / 2;   // ~14.84M floats = 59.4 MB

typedef __attribute__((ext_vector_type(8)))  short short8x;
typedef __attribute__((ext_vector_type(16))) float f32x16;

__device__ __forceinline__ float ldf(const float* p, int i) { return p[i]; }
__device__ __forceinline__ float ldf(const __hip_bfloat16* p, int i) { return __bfloat162float(p[i]); }
__device__ __forceinline__ void stf(float* p, size_t i, float v) { p[i] = v; }
__device__ __forceinline__ void stf(__hip_bfloat16* p, size_t i, float v) { p[i] = __float2bfloat16(v); }
__device__ __forceinline__ float4 ld4(const float* p, size_t i) { return *(const float4*)(p + i); }
__device__ __forceinline__ float4 ld4(const __hip_bfloat16* p, size_t i) {
    ushort4 u = *(const ushort4*)(p + i);
    return make_float4(__uint_as_float((unsigned)u.x << 16),
                       __uint_as_float((unsigned)u.y << 16),
                       __uint_as_float((unsigned)u.z << 16),
                       __uint_as_float((unsigned)u.w << 16));
}
// Split f32 -> bf16 hi (truncate) + bf16 lo (residual, truncate).
__device__ __forceinline__ void split_bf(float v, unsigned short& h, unsigned short& l) {
    h = (unsigned short)(__float_as_uint(v) >> 16);
    float r = v - __uint_as_float((unsigned)h << 16);
    l = (unsigned short)(__float_as_uint(r) >> 16);
}

// Fallback dtype detect from s_mask (all ones): f32 -> 0x3F800000, bf16x2 -> 0x3F803F80
__global__ void k_detect(const unsigned* smask_raw, int* flag) {
    if (threadIdx.x == 0) *flag = (smask_raw[0] == 0x3F803F80u) ? 1 : 0;
}

// ---------------- prep (4193 blocks x 256) ----------------
// blk [0,1728):      wnodeT hi/lo elementwise
// blk [1728,3168):   woutT hi/lo elementwise
// blk [3168,4192):   s LayerNorm, 4 rows/block, wave-per-row
// blk 4192:          z-weight prep (W' = diag(zsc)@[wb|wdz], bvec, csum)
template <typename T>
__global__ __launch_bounds__(256) void k_prep_s(const T* s, const T* lns_sc, const T* lns_bi,
    const T* wq, const T* wk, const T* wv, const T* wqp, const T* wkvp, const T* wout,
    const T* wb, const T* wdz, const T* zsc, const T* zbi, float* wsf,
    const int* flag, int want)
{
    if (flag && *flag != want) return;
    int vb = blockIdx.x, t = threadIdx.x;
    unsigned short* wntH = (unsigned short*)(wsf + O_WNTH);
    unsigned short* wntL = (unsigned short*)(wsf + O_WNTL);
    unsigned short* wotH = (unsigned short*)(wsf + O_WOTH);
    unsigned short* wotL = (unsigned short*)(wsf + O_WOTL);
    unsigned short* slnH = (unsigned short*)(wsf + O_SLNH);
    unsigned short* slnL = (unsigned short*)(wsf + O_SLNL);
    if (vb < 1728) {
        int idx = vb * 256 + t;                     // exactly 1152*384
        int n = idx / 384, k = idx - n * 384;
        float v;
        if      (n < 192) v = ldf(wq,  k * 192 + n);
        else if (n < 384) v = ldf(wk,  k * 192 + n - 192);
        else if (n < 576) v = ldf(wv,  k * 192 + n - 384);
        else if (n < 720) v = ldf(wqp, k * 144 + n - 576);
        else              v = ldf(wkvp, k * 432 + n - 720);
        unsigned short h, l; split_bf(v, h, l);
        wntH[n * 384 + k] = h; wntL[n * 384 + k] = l;
    } else if (vb < 3168) {
        int idx = (vb - 1728) * 256 + t;            // exactly 384*960
        int n = idx / 960, k = idx - n * 960;
        float v = ldf(wout, k * 384 + n);
        unsigned short h, l; split_bf(v, h, l);
        wotH[n * 960 + k] = h; wotL[n * 960 + k] = l;
    } else if (vb < 4192) {
        int row = (vb - 3168) * 4 + (t >> 6), lane = t & 63;
        float x[6]; float sum = 0, sq = 0;
        #pragma unroll
        for (int j = 0; j < 6; j++) {
            float v = ldf(s, row * CS + lane + 64 * j);
            x[j] = v; sum += v; sq += v * v;
        }
        #pragma unroll
        for (int m = 32; m; m >>= 1) { sum += __shfl_xor(sum, m, 64); sq += __shfl_xor(sq, m, 64); }
        float mean = sum * (1.f / CS);
        float var  = sq * (1.f / CS) - mean * mean;
        float r = rsqrtf(var + 1e-5f);
        #pragma unroll
        for (int j = 0; j < 6; j++) {
            int c = lane + 64 * j;
            float y = (x[j] - mean) * r * ldf(lns_sc, c) + ldf(lns_bi, c);
            unsigned short h, l; split_bf(y, h, l);
            slnH[(size_t)row * CS + c] = h; slnL[(size_t)row * CS + c] = l;
        }
    } else {
        if (t < 128) {
            float sc = ldf(zsc, t);
            for (int o = 0; o < 48; o++) {
                float w = 0.f;
                if (o < 12)      w = ldf(wb, t * 12 + o);
                else if (o < 44) w = ldf(wdz, t * 32 + o - 12);
                wsf[O_WZP + t * 48 + o] = sc * w;
            }
        } else if (t < 176) {
            int o = t - 128;
            float acc = 0.f;
            if (o < 44)
                for (int c = 0; c < 128; c++)
                    acc += ldf(zbi, c) * (o < 12 ? ldf(wb, c * 12 + o) : ldf(wdz, c * 32 + o - 12));
            wsf[O_BVEC + o] = acc;
        } else if (t < 224) {
            int o = t - 176;
            float acc = 0.f;
            if (o < 44)
                for (int c = 0; c < 128; c++)
                    acc += ldf(zsc, c) * (o < 12 ? ldf(wb, c * 12 + o) : ldf(wdz, c * 32 + o - 12));
            wsf[O_CSUM + o] = acc;
        }
    }
}

// ---------------- z-GEMM: one edge per thread, no barriers in main loop -----------------
// acc[44] in registers; W' broadcast from LDS (wave-uniform addr -> conflict-free);
// LN folded in epilogue: zout = rs*acc - rs*mu*csum + bvec.
template <typename T>
__global__ __launch_bounds__(256) void k_zg2(const T* z, const float* wzp, const float* bvec,
                                             const float* csum, float* zout,
                                             const int* flag, int want)
{
    if (flag && *flag != want) return;
    __shared__ float Ws[6144];
    __shared__ float BC[96];           // bvec[0..48) | csum[48..96)
    int t = threadIdx.x;
    for (int i = t; i < 6144; i += 256) Ws[i] = wzp[i];
    if (t < 48) { BC[t] = bvec[t]; BC[48 + t] = csum[t]; }
    __syncthreads();
    size_t e = (size_t)blockIdx.x * 256 + t;
    float4 acc4[11];
    #pragma unroll
    for (int i = 0; i < 11; i++) acc4[i] = make_float4(0.f, 0.f, 0.f, 0.f);
    float sum = 0.f, sq = 0.f;
    for (int c = 0; c < CZ; c += 4) {
        float4 zv = ld4(z, e * CZ + c);
        sum += zv.x + zv.y + zv.z + zv.w;
        sq  += zv.x * zv.x + zv.y * zv.y + zv.z * zv.z + zv.w * zv.w;
        float zz[4] = {zv.x, zv.y, zv.z, zv.w};
        #pragma unroll
        for (int j = 0; j < 4; j++) {
            const float4* wr = (const float4*)&Ws[(c + j) * 48];
            float zc = zz[j];
            #pragma unroll
            for (int i = 0; i < 11; i++) {
                float4 w = wr[i];
                acc4[i].x += zc * w.x; acc4[i].y += zc * w.y;
                acc4[i].z += zc * w.z; acc4[i].w += zc * w.w;
            }
        }
    }
    float mu = sum * (1.f / CZ);
    float rs = rsqrtf(sq * (1.f / CZ) - mu * mu + 1e-5f);
    float* zr = zout + e * ZOC;
    #pragma unroll
    for (int i = 0; i < 11; i++) {
        float4 a = acc4[i];
        float4 bv = *(const float4*)&BC[i * 4];
        float4 cs = *(const float4*)&BC[48 + i * 4];
        float4 o;
        o.x = rs * a.x - rs * mu * cs.x + bv.x;
        o.y = rs * a.y - rs * mu * cs.y + bv.y;
        o.z = rs * a.z - rs * mu * cs.z + bv.z;
        o.w = rs * a.w - rs * mu * cs.w + bv.w;
        *(float4*)(zr + i * 4) = o;                 // 44 = 11*4, 16B aligned
    }
}

// ---------------- MFMA split-bf16 64x64 tile (one wave, no LDS) -------------------------
#define MFMA3(C, AH, AL, BH, BL)                                              \
    C = __builtin_amdgcn_mfma_f32_32x32x16_bf16(AH, BH, C, 0, 0, 0);          \
    C = __builtin_amdgcn_mfma_f32_32x32x16_bf16(AH, BL, C, 0, 0, 0);          \
    C = __builtin_amdgcn_mfma_f32_32x32x16_bf16(AL, BH, C, 0, 0, 0);

template <typename TO>
__global__ __launch_bounds__(64) void k_mgemm_s(const unsigned short* AH, const unsigned short* AL,
    int lda, const unsigned short* BH, const unsigned short* BL, int ldb,
    TO* C, int ldc, int Kdim, const int* flag, int want)
{
    if (flag && *flag != want) return;
    int bx = blockIdx.x, by = blockIdx.y;
    int l = threadIdx.x, r = l & 31, g = l >> 5;
    size_t a0 = (size_t)(bx * 64 + r) * lda + 8 * g;
    size_t a1 = a0 + (size_t)32 * lda;
    size_t b0 = (size_t)(by * 64 + r) * ldb + 8 * g;
    size_t b1 = b0 + (size_t)32 * ldb;
    f32x16 c00 = {}, c01 = {}, c10 = {}, c11 = {};
    for (int kt = 0; kt < Kdim; kt += 16) {
        short8x aH0 = *(const short8x*)(AH + a0 + kt), aH1 = *(const short8x*)(AH + a1 + kt);
        short8x aL0 = *(const short8x*)(AL + a0 + kt), aL1 = *(const short8x*)(AL + a1 + kt);
        short8x bH0 = *(const short8x*)(BH + b0 + kt), bH1 = *(const short8x*)(BH + b1 + kt);
        short8x bL0 = *(const short8x*)(BL + b0 + kt), bL1 = *(const short8x*)(BL + b1 + kt);
        MFMA3(c00, aH0, aL0, bH0, bL0)
        MFMA3(c01, aH0, aL0, bH1, bL1)
        MFMA3(c10, aH1, aL1, bH0, bL0)
        MFMA3(c11, aH1, aL1, bH1, bL1)
    }
    // D layout: col = lane&31, row = (reg&3) + 8*(reg>>2) + 4*(lane>>5)
    #pragma unroll
    for (int reg = 0; reg < 16; reg++) {
        int row = (reg & 3) + 8 * (reg >> 2) + 4 * g;
        size_t rm = (size_t)(bx * 64 + row);
        int cn = by * 64 + r;
        stf(C, rm * ldc + cn,             c00[reg]);
        stf(C, rm * ldc + cn + 32,        c01[reg]);
        stf(C, (rm + 32) * ldc + cn,      c10[reg]);
        stf(C, (rm + 32) * ldc + cn + 32, c11[reg]);
    }
}

// ---------------- attention: ONE NODE / 128-thread block (2 waves), grid 4096 -----------
// LDS: S[1088] f32 (~4.4 KB) + J[32].  o / o_pair / dists written DIRECT to global;
// only o_pt raw (288) stages in LDS for the M-transform.
// S layout: q[0,192) qp[192,336) hw[336,348) M[348,357) msk[360,392) l[392,788) optraw[788,1076)
template <typename T>
__global__ __launch_bounds__(128, 8) void k_attn2(const float* P, const float* zout,
    const int* eidx, const T* smask, const T* rot, const T* hwq,
    unsigned short* featH, unsigned short* featL, const int* flag, int want)
{
    if (flag && *flag != want) return;
    __shared__ float S[1088];
    __shared__ int J[32];
    int bid = blockIdx.x, t = threadIdx.x;
    int node = ((bid & 7) << 9) + (bid >> 3);      // XCD-chunked: XCD x owns nodes [x*512,(x+1)*512)
    int b = node >> 10;
    const float* Pn = P + (size_t)node * NCOLS;
    for (int u = t; u < 336; u += 128)
        S[u] = (u < 192) ? Pn[u] : Pn[384 + u];    // q | q_pts (cols 576..719)
    if (t < 32) {
        int j = eidx[node * Kk + t];
        J[t] = b * Nn + j;
        S[360 + t] = ldf(smask, node) * ldf(smask, b * Nn + j);
    } else if (t < 44) {
        int h = t - 32;
        float x = ldf(hwq, h);
        S[336 + h] = logf(1.f + expf(x)) * 0.13608276348795434f;   // softplus * sqrt(1/54)
    } else if (t < 53) {
        int u = t - 44;
        int i = u / 3, jj = u - i * 3;
        float m = 0;
        #pragma unroll
        for (int l2 = 0; l2 < 3; l2++)
            m += ldf(rot, node * 9 + l2 * 3 + i) * ldf(rot, node * 9 + l2 * 3 + jj);
        S[348 + u] = m;                            // M = R^T R
    }
    __syncthreads();
    // logits + softmax: 3 iterations x 128 threads; (h,k) = (u>>5, u&31);
    // shuffle reduce stays within 32-lane groups (masks 16..1).
    #pragma unroll
    for (int it = 0; it < 3; it++) {
        int u = t + 128 * it;
        int h = u >> 5, k = u & 31;
        const float* Pj = P + (size_t)J[k] * NCOLS;
        float qk = 0;
        const float4* pk4 = (const float4*)(Pj + 192 + h * 16);
        const float4* qs4 = (const float4*)(S + h * 16);
        #pragma unroll
        for (int c4 = 0; c4 < 4; c4++) {
            float4 pv = pk4[c4], qv = qs4[c4];
            qk += qv.x * pv.x + qv.y * pv.y + qv.z * pv.z + qv.w * pv.w;
        }
        float M00 = S[348], M01 = S[349], M02 = S[350],
              M11 = S[352], M12 = S[353], M22 = S[356];
        const float4* pp4 = (const float4*)(Pj + 720 + h * 36);
        const float4* qp4 = (const float4*)(S + 192 + h * 12);
        float4 A0 = pp4[0], A1 = pp4[1], A2 = pp4[2];
        float4 B0 = qp4[0], B1 = qp4[1], B2 = qp4[2];
        float d[12] = {B0.x - A0.x, B0.y - A0.y, B0.z - A0.z, B0.w - A0.w,
                       B1.x - A1.x, B1.y - A1.y, B1.z - A1.z, B1.w - A1.w,
                       B2.x - A2.x, B2.y - A2.y, B2.z - A2.z, B2.w - A2.w};
        float sq = 0;
        #pragma unroll
        for (int p = 0; p < 4; p++) {
            float d0 = d[p * 3], d1 = d[p * 3 + 1], d2 = d[p * 3 + 2];
            sq += M00 * d0 * d0 + M11 * d1 * d1 + M22 * d2 * d2
                + 2.f * (M01 * d0 * d1 + M02 * d0 * d2 + M12 * d1 * d2);
        }
        float logit = qk * 0.14433756729740643f
                    + 0.5773502691896258f * zout[((size_t)node * Kk + k) * ZOC + h]
                    - 0.5f * S[336 + h] * sq
                    + 1e5f * (S[360 + k] - 1.f);
        float mx = logit;
        #pragma unroll
        for (int m = 16; m; m >>= 1) mx = fmaxf(mx, __shfl_xor(mx, m, 64));
        float e = expf(logit - mx);
        float ssum = e;
        #pragma unroll
        for (int m = 16; m; m >>= 1) ssum += __shfl_xor(ssum, m, 64);
        S[392 + h * 33 + k] = e / ssum;            // stride-33: conflict-free
    }
    __syncthreads();
    // accumulation: 216 float4 tasks: o(48) | o_pt raw(72) | o_pair(96)
    size_t fb = (size_t)node * FEAT;
    for (int u = t; u < 216; u += 128) {
        int h, off, fbase, pair = 0;
        if (u < 48)       { h = u >> 2; off = 384 + h * 16 + (u & 3) * 4; fbase = h * 16 + (u & 3) * 4; }
        else if (u < 120) { int v = u - 48;  h = v / 6; int q = v - h * 6;
                            off = 732 + h * 36 + q * 4; fbase = 192 + h * 24 + q * 4; }
        else              { int v = u - 120; h = v >> 3;
                            off = 12 + (v & 7) * 4; fbase = 576 + h * 32 + (v & 7) * 4; pair = 1; }
        float4 acc = {0.f, 0.f, 0.f, 0.f};
        const float* lrow = S + 392 + h * 33;
        if (!pair) {
            #pragma unroll 8
            for (int k = 0; k < 32; k++) {
                float lw = lrow[k];
                float4 pv = *(const float4*)(P + (size_t)J[k] * NCOLS + off);
                acc.x += lw * pv.x; acc.y += lw * pv.y; acc.z += lw * pv.z; acc.w += lw * pv.w;
            }
        } else {
            const float* zr = zout + (size_t)node * Kk * ZOC + off;
            #pragma unroll 8
            for (int k = 0; k < 32; k++) {
                float lw = lrow[k];
                float4 pv = *(const float4*)(zr + k * ZOC);
                acc.x += lw * pv.x; acc.y += lw * pv.y; acc.z += lw * pv.z; acc.w += lw * pv.w;
            }
        }
        if (u >= 48 && u < 120) {
            *(float4*)&S[788 + (fbase - 192)] = acc;             // o_pt raw -> LDS
        } else {
            ushort4 hi, lo;
            split_bf(acc.x, hi.x, lo.x); split_bf(acc.y, hi.y, lo.y);
            split_bf(acc.z, hi.z, lo.z); split_bf(acc.w, hi.w, lo.w);
            *(ushort4*)(featH + fb + fbase) = hi;                // direct global write
            *(ushort4*)(featL + fb + fbase) = lo;
        }
    }
    __syncthreads();
    // apply M to o_pt, compute dists; write both direct to global
    if (t < 96) {
        float r0 = S[788 + t * 3 + 0];
        float r1 = S[788 + t * 3 + 1];
        float r2 = S[788 + t * 3 + 2];
        float o0 = S[348] * r0 + S[349] * r1 + S[350] * r2;
        float o1 = S[351] * r0 + S[352] * r1 + S[353] * r2;
        float o2 = S[354] * r0 + S[355] * r1 + S[356] * r2;
        unsigned short h, l;
        split_bf(o0, h, l); featH[fb + 192 + t * 3 + 0] = h; featL[fb + 192 + t * 3 + 0] = l;
        split_bf(o1, h, l); featH[fb + 192 + t * 3 + 1] = h; featL[fb + 192 + t * 3 + 1] = l;
        split_bf(o2, h, l); featH[fb + 192 + t * 3 + 2] = h; featL[fb + 192 + t * 3 + 2] = l;
        float dd = sqrtf(o0 * o0 + o1 * o1 + o2 * o2 + 1e-8f);
        split_bf(dd, h, l); featH[fb + 480 + t] = h; featL[fb + 480 + t] = l;
    }
}

// ---------------- Host side -------------------------------------------------------------
template <typename T, typename TO>
static void run_path(const void* s, const void* z, const int* eidx, const void* rot,
                     const void* smask, const void* lns_sc, const void* lns_bi,
                     const void* wq, const void* wk, const void* wv, const void* wqp,
                     const void* wkvp, const void* wb, const void* wdz, const void* zsc,
                     const void* zbi, const void* hwq, const void* wout,
                     float* wsf, void* dout, const int* fg, int want, hipStream_t stream)
{
    unsigned short* slnH = (unsigned short*)(wsf + O_SLNH);
    unsigned short* slnL = (unsigned short*)(wsf + O_SLNL);
    unsigned short* wntH = (unsigned short*)(wsf + O_WNTH);
    unsigned short* wntL = (unsigned short*)(wsf + O_WNTL);
    unsigned short* wotH = (unsigned short*)(wsf + O_WOTH);
    unsigned short* wotL = (unsigned short*)(wsf + O_WOTL);
    unsigned short* featH = (unsigned short*)(wsf + O_FEATH);
    unsigned short* featL = (unsigned short*)(wsf + O_FEATL);

    k_prep_s<T><<<NPREP, 256, 0, stream>>>((const T*)s, (const T*)lns_sc, (const T*)lns_bi,
        (const T*)wq, (const T*)wk, (const T*)wv, (const T*)wqp, (const T*)wkvp,
        (const T*)wout, (const T*)wb, (const T*)wdz, (const T*)zsc, (const T*)zbi, wsf, fg, want);
    k_zg2<T><<<NEDGE / 256, 256, 0, stream>>>((const T*)z, wsf + O_WZP, wsf + O_BVEC,
        wsf + O_CSUM, wsf + O_ZOUT, fg, want);
    k_mgemm_s<float><<<dim3(64, 18), 64, 0, stream>>>(slnH, slnL, CS, wntH, wntL, CS,
        wsf + O_P, NCOLS, CS, fg, want);
    k_attn2<T><<<NNODE, 128, 0, stream>>>(wsf + O_P, wsf + O_ZOUT, eidx, (const T*)smask,
        (const T*)rot, (const T*)hwq, featH, featL, fg, want);
    k_mgemm_s<TO><<<dim3(64, 6), 64, 0, stream>>>(featH, featL, FEAT, wotH, wotL, FEAT,
        (TO*)dout, CS, FEAT, fg, want);
}

extern "C" void kernel_launch(void* const* d_in, const int* in_sizes, int n_in,
                              void* d_out, int out_size, void* d_ws, size_t ws_size,
                              hipStream_t stream) {
    float* wsf = (float*)d_ws;
    int* flag = (int*)d_ws;
    const void* s = d_in[0];   const void* z = d_in[1];
    const int* eidx = (const int*)d_in[2];
    const void* rot = d_in[3];                         // d_in[4] trans: unused (cancels exactly)
    const void* smask = d_in[5];
    const void* lns_sc = d_in[6]; const void* lns_bi = d_in[7];
    const void* lnz_sc = d_in[8]; const void* lnz_bi = d_in[9];
    const void* wq = d_in[10]; const void* wk = d_in[11]; const void* wv = d_in[12];
    const void* wqp = d_in[13]; const void* wkvp = d_in[14];
    const void* wb = d_in[15]; const void* wdz = d_in[16];
    const void* hwq = d_in[17]; const void* wout = d_in[18];

    int mode = -1;  // 0 = f32, 1 = bf16, -1 = unknown -> guarded dual launch
    if (in_sizes) {
        if (in_sizes[0] == NNODE * CS * 4) mode = 0;
        else if (in_sizes[0] == NNODE * CS * 2) mode = 1;
    }

    if (mode == 0) {
        run_path<float, float>(s, z, eidx, rot, smask, lns_sc, lns_bi, wq, wk, wv, wqp, wkvp,
                               wb, wdz, lnz_sc, lnz_bi, hwq, wout, wsf, d_out,
                               nullptr, 0, stream);
    } else if (mode == 1) {
        run_path<__hip_bfloat16, __hip_bfloat16>(s, z, eidx, rot, smask, lns_sc, lns_bi,
                               wq, wk, wv, wqp, wkvp, wb, wdz, lnz_sc, lnz_bi, hwq, wout,
                               wsf, d_out, nullptr, 0, stream);
    } else {
        k_detect<<<1, 64, 0, stream>>>((const unsigned*)smask, flag);
        run_path<float, float>(s, z, eidx, rot, smask, lns_sc, lns_bi, wq, wk, wv, wqp, wkvp,
                               wb, wdz, lnz_sc, lnz_bi, hwq, wout, wsf, d_out,
                               flag, 0, stream);
        run_path<__hip_bfloat16, __hip_bfloat16>(s, z, eidx, rot, smask, lns_sc, lns_bi,
                               wq, wk, wv, wqp, wkvp, wb, wdz, lnz_sc, lnz_bi, hwq, wout,
                               wsf, d_out, flag, 1, stream);
    }
}